// Round 9
// baseline (209.442 us; speedup 1.0000x reference)
//
#include <hip/hip_runtime.h>
#include <hip/hip_bf16.h>

#define N_NODES 50000
#define N_EDGES 800000
#define D 64
#define NB 196        // coarse buckets: dst>>8 -> 0..195
#define CHUNK_E 4096  // edges per partition block
#define NPB 196      // ceil(800000/4096)

typedef __attribute__((ext_vector_type(8))) short short8v;   // 8 bf16 (4 VGPRs)
typedef __attribute__((ext_vector_type(4))) float float4v;   // 4 fp32 acc

// ---------- helpers ----------
__device__ __forceinline__ float b2f(unsigned short h) {
    return __uint_as_float(((unsigned)h) << 16);
}
__device__ __forceinline__ unsigned short f2b(float f) {
    __hip_bfloat16 t = __float2bfloat16(f);
    return *reinterpret_cast<unsigned short*>(&t);
}

// ---------- kernel 0: runtime dtype / index-width detection ----------
__global__ void detect_mode(const void* feat, const void* srcv, unsigned* flags) {
    const int t = threadIdx.x;          // 128 threads = 2 waves
    if (t < 64) {
        const unsigned short* p = (const unsigned short*)feat;
        float x = b2f(p[2 * t]);
        float a = fabsf(x);
        bool insane = !(a <= 64.f) || (x != 0.f && a < 9.3132e-10f);
        unsigned long long m = __ballot(insane);
        if (t == 0) flags[0] = (__popcll(m) >= 8) ? 1u : 0u;
    } else {
        const int* s32 = (const int*)srcv;
        int v = s32[2 * (t - 64) + 1];
        unsigned long long m = __ballot(v == 0);
        if (t == 64) flags[1] = (__popcll(m) >= 32) ? 1u : 0u;
    }
}

// ---------- kernel 0b: pre-permute W into MFMA B-fragment order ----------
// frag layout: WTfrag[(col*4 + h*2 + q)*8 + j] = Wt[(h*32 + q*8 + j)*64 + col]
// so a B-fragment (col,h,q) is one contiguous 16-byte load.
__global__ __launch_bounds__(256)
void prep_w(const void* __restrict__ Wtv, const void* __restrict__ btv,
            const void* __restrict__ Wpv, const void* __restrict__ bpv,
            const unsigned* __restrict__ flags,
            unsigned short* __restrict__ WTfrag, unsigned short* __restrict__ WPfrag,
            float* __restrict__ bias_sum) {
    if (flags[0]) return;                              // fp32 fallback uses raw W
    const int t = threadIdx.x;
    const unsigned short* Wt = (const unsigned short*)Wtv;
    const unsigned short* Wp = (const unsigned short*)Wpv;
#pragma unroll
    for (int i = 0; i < 16; ++i) {
        int e = i * 256 + t;                           // coalesced read
        int k = e >> 6, n = e & 63;
        int pos = (n * 4 + (k >> 5) * 2 + ((k >> 3) & 3)) * 8 + (k & 7);
        WTfrag[pos] = Wt[e];
        WPfrag[pos] = Wp[e];
    }
    if (t < 64)
        bias_sum[t] = b2f(((const unsigned short*)btv)[t])
                    + b2f(((const unsigned short*)bpv)[t]);
}

// ---------- kernel 1: MFMA node transforms (1 strip/wave, frag-ordered B) ----------
// T = feat@Wt -> T16 (ws) ; C = feat@Wt + feat@Wp + bt + bp -> d_out
__global__ __launch_bounds__(256)
void node_both(const void* __restrict__ featv,
               const unsigned short* __restrict__ WTfrag,
               const unsigned short* __restrict__ WPfrag,
               const float* __restrict__ bias_sum,
               const void* __restrict__ Wtv, const void* __restrict__ btv,
               const void* __restrict__ Wpv, const void* __restrict__ bpv,
               const unsigned* __restrict__ flags,
               unsigned short* __restrict__ T16, void* __restrict__ outv) {
    const int lane = threadIdx.x & 63;
    const int wid  = threadIdx.x >> 6;
    const int w = blockIdx.x * 4 + wid;

    if (flags[0] == 0) {
        // ---- bf16 MFMA path: exactly one 16-row strip per wave ----
        if (w >= N_NODES / 16) return;                 // 3125 strips
        const int m = lane & 15, q = lane >> 4;
        const short8v* BT = (const short8v*)WTfrag;    // idx = col*4 + h*2 + q
        const short8v* BP = (const short8v*)WPfrag;

        // A frags: A[m=lane&15][k=q*8+j] ; two k-halves
        const short* fr = (const short*)featv + (w * 16 + m) * D + q * 8;
        short8v A0 = *(const short8v*)fr;
        short8v A1 = *(const short8v*)(fr + 32);

        unsigned short* Cout = (unsigned short*)outv;
#pragma unroll
        for (int c = 0; c < 4; ++c) {
            const int col = 16 * c + m;
            short8v Bt0 = BT[col * 4 + q];             // h=0
            short8v Bt1 = BT[col * 4 + 2 + q];         // h=1
            short8v Bp0 = BP[col * 4 + q];
            short8v Bp1 = BP[col * 4 + 2 + q];
            float bs = bias_sum[col];
            float4v accT = (float4v){0.f, 0.f, 0.f, 0.f};
            float4v accP = (float4v){bs, bs, bs, bs};
            accT = __builtin_amdgcn_mfma_f32_16x16x32_bf16(A0, Bt0, accT, 0, 0, 0);
            accT = __builtin_amdgcn_mfma_f32_16x16x32_bf16(A1, Bt1, accT, 0, 0, 0);
            accP = __builtin_amdgcn_mfma_f32_16x16x32_bf16(A0, Bp0, accP, 0, 0, 0);
            accP = __builtin_amdgcn_mfma_f32_16x16x32_bf16(A1, Bp1, accP, 0, 0, 0);
            // C/D layout: col = lane&15 (+16c), row = q*4 + reg
#pragma unroll
            for (int r = 0; r < 4; ++r) {
                const int row = w * 16 + q * 4 + r;
                T16[row * D + col]  = f2b(accT[r]);
                Cout[row * D + col] = f2b(accT[r] + accP[r]);
            }
        }
    } else {
        // ---- fp32 fallback: shuffle GEMM (T stored bf16 best-effort) ----
        const float* F  = (const float*)featv;
        const float* Wt = (const float*)Wtv;
        const float* Wp = (const float*)Wpv;
        float wt[D], wp[D];
#pragma unroll
        for (int k = 0; k < D; ++k) { wt[k] = Wt[k * D + lane]; wp[k] = Wp[k * D + lane]; }
        const float bsum = ((const float*)btv)[lane] + ((const float*)bpv)[lane];
        float* Cout = (float*)outv;
        const int nwaves = gridDim.x * 4;
        for (int s = w; s < N_NODES / 16; s += nwaves) {
            for (int r = s * 16; r < s * 16 + 16; ++r) {
                float x = F[r * D + lane];
                float at = 0.f, ap = 0.f;
#pragma unroll
                for (int k = 0; k < D; ++k) {
                    float f = __shfl(x, k, 64);
                    at = fmaf(f, wt[k], at);
                    ap = fmaf(f, wp[k], ap);
                }
                T16[r * D + lane]  = f2b(at);
                Cout[r * D + lane] = at + ap + bsum;
            }
        }
    }
}

// ---------- kernel 2: coarse bucket counts (LDS-aggregated) ----------
__global__ __launch_bounds__(256)
void coarse_count(const void* __restrict__ dstv, const unsigned* __restrict__ flags,
                  unsigned* __restrict__ c_cnt) {
    __shared__ unsigned cnt[NB];
    const int t = threadIdx.x;
    if (t < NB) cnt[t] = 0;
    __syncthreads();
    const unsigned idx64 = flags[1];
    const int base = blockIdx.x * CHUNK_E;
#pragma unroll
    for (int j = 0; j < CHUNK_E / 256; ++j) {
        int e = base + j * 256 + t;
        if (e < N_EDGES) {
            int d = idx64 ? (int)((const long long*)dstv)[e] : ((const int*)dstv)[e];
            d = min(max(d, 0), N_NODES - 1);
            atomicAdd(&cnt[d >> 8], 1u);
        }
    }
    __syncthreads();
    if (t < NB && cnt[t]) atomicAdd(&c_cnt[t], cnt[t]);
}

// ---------- kernel 3: scan of NB coarse counts -> c_off, c_cur ----------
__global__ __launch_bounds__(256)
void scanNB(const unsigned* __restrict__ c_cnt, unsigned* __restrict__ c_off,
            unsigned* __restrict__ c_cur, unsigned* __restrict__ offsets) {
    __shared__ unsigned sm[256];
    const int t = threadIdx.x;
    unsigned v = (t < NB) ? c_cnt[t] : 0u;
    sm[t] = v;
    __syncthreads();
    for (int off = 1; off < 256; off <<= 1) {
        unsigned u = (t >= off) ? sm[t - off] : 0u;
        __syncthreads();
        sm[t] += u;
        __syncthreads();
    }
    if (t < NB) { c_off[t] = sm[t] - v; c_cur[t] = sm[t] - v; }
    if (t == 0) { c_off[NB] = N_EDGES; offsets[N_NODES] = N_EDGES; }
}

// ---------- kernel 4: coarse partition of packed (dst<<16|src) ----------
__global__ __launch_bounds__(256)
void coarse_scatter(const void* __restrict__ srcv, const void* __restrict__ dstv,
                    const unsigned* __restrict__ flags,
                    unsigned* __restrict__ c_cur, unsigned* __restrict__ packed) {
    __shared__ unsigned h[NB];
    const int t = threadIdx.x;
    if (t < NB) h[t] = 0;
    __syncthreads();
    const unsigned idx64 = flags[1];
    const int base = blockIdx.x * CHUNK_E;
    unsigned pk[CHUNK_E / 256];
#pragma unroll
    for (int j = 0; j < CHUNK_E / 256; ++j) {
        int e = base + j * 256 + t;
        unsigned p = 0xFFFFFFFFu;                      // sentinel (dst<=49999 < 0xFFFF)
        if (e < N_EDGES) {
            int s, d;
            if (idx64) {
                s = (int)((const long long*)srcv)[e];
                d = (int)((const long long*)dstv)[e];
            } else {
                s = ((const int*)srcv)[e];
                d = ((const int*)dstv)[e];
            }
            s = min(max(s, 0), N_NODES - 1);
            d = min(max(d, 0), N_NODES - 1);
            p = ((unsigned)d << 16) | (unsigned)s;
            atomicAdd(&h[d >> 8], 1u);
        }
        pk[j] = p;
    }
    __syncthreads();
    // one reservation atomic per (block,bucket); h becomes the LDS write cursor
    if (t < NB) h[t] = atomicAdd(&c_cur[t], h[t]);
    __syncthreads();
#pragma unroll
    for (int j = 0; j < CHUNK_E / 256; ++j) {
        unsigned p = pk[j];
        if (p != 0xFFFFFFFFu) {
            unsigned pos = atomicAdd(&h[p >> 24], 1u); // p>>24 == dst>>8
            packed[pos] = p;
        }
    }
}

// ---------- kernel 5: per-bucket node hist + scan + fine scatter (all LDS) ----------
__global__ __launch_bounds__(256)
void bucket_build(const unsigned* __restrict__ c_off, const unsigned* __restrict__ packed,
                  unsigned* __restrict__ offsets, unsigned short* __restrict__ esrc) {
    __shared__ unsigned h[256];   // node counts -> node cursors
    __shared__ unsigned s[256];   // scan buffer
    const int t = threadIdx.x;
    const int b = blockIdx.x;
    const int estart = (int)c_off[b];
    const int eend   = (int)c_off[b + 1];
    h[t] = 0;
    __syncthreads();
    for (int i = estart + t; i < eend; i += 256)
        atomicAdd(&h[(packed[i] >> 16) & 255], 1u);
    __syncthreads();
    unsigned c = h[t];
    s[t] = c;
    __syncthreads();
    for (int off = 1; off < 256; off <<= 1) {
        unsigned u = (t >= off) ? s[t - off] : 0u;
        __syncthreads();
        s[t] += u;
        __syncthreads();
    }
    unsigned pos0 = (unsigned)estart + s[t] - c;       // CSR start for this node
    h[t] = pos0;                                       // own slot only
    const int node = (b << 8) + t;
    if (node < N_NODES) offsets[node] = pos0;
    __syncthreads();
    for (int i = estart + t; i < eend; i += 256) {
        unsigned p = packed[i];
        unsigned pos = atomicAdd(&h[(p >> 16) & 255], 1u);
        esrc[pos] = (unsigned short)(p & 0xFFFFu);
    }
}

// ---------- kernel 6: per-node segmented min + fused epilogue ----------
// lane = (edge-group g = lane>>4, feature-quad fb = (lane&15)*4)
// out[n] = C[n] - min ; C read from d_out, overwritten in place (own row only)
__global__ __launch_bounds__(256)
void min_gather(const unsigned* __restrict__ offsets, const unsigned short* __restrict__ esrc,
                const unsigned short* __restrict__ T16, const unsigned* __restrict__ flags,
                void* __restrict__ outv) {
    const unsigned fp32mode = flags[0];
    const int lane = threadIdx.x & 63;
    const int wid  = threadIdx.x >> 6;
    const int n = (blockIdx.x << 2) + wid;             // grid exact: 12500*4 waves
    const int g  = lane >> 4;
    const int fb = (lane & 15) << 2;
    const int a = (int)offsets[n];
    const int b = (int)offsets[n + 1];
    const float FMAX = __uint_as_float(0x7f7fffffu);
    float m0 = FMAX, m1 = FMAX, m2 = FMAX, m3 = FMAX;

    int i = a + g;
    for (; i + 4 < b; i += 8) {                        // 2 gathers in flight
        int s0 = (int)esrc[i], s1 = (int)esrc[i + 4];
        uint2 v0 = *(const uint2*)(T16 + s0 * D + fb);
        uint2 v1 = *(const uint2*)(T16 + s1 * D + fb);
        m0 = fminf(m0, fminf(b2f((unsigned short)v0.x), b2f((unsigned short)v1.x)));
        m1 = fminf(m1, fminf(b2f((unsigned short)(v0.x >> 16)), b2f((unsigned short)(v1.x >> 16))));
        m2 = fminf(m2, fminf(b2f((unsigned short)v0.y), b2f((unsigned short)v1.y)));
        m3 = fminf(m3, fminf(b2f((unsigned short)(v0.y >> 16)), b2f((unsigned short)(v1.y >> 16))));
    }
    if (i < b) {
        int s0 = (int)esrc[i];
        uint2 v0 = *(const uint2*)(T16 + s0 * D + fb);
        m0 = fminf(m0, b2f((unsigned short)v0.x));
        m1 = fminf(m1, b2f((unsigned short)(v0.x >> 16)));
        m2 = fminf(m2, b2f((unsigned short)v0.y));
        m3 = fminf(m3, b2f((unsigned short)(v0.y >> 16)));
    }
    // combine the 4 edge-groups: lanes l, l^16, l^32, l^48 share features
    m0 = fminf(m0, __shfl_xor(m0, 16, 64)); m0 = fminf(m0, __shfl_xor(m0, 32, 64));
    m1 = fminf(m1, __shfl_xor(m1, 16, 64)); m1 = fminf(m1, __shfl_xor(m1, 32, 64));
    m2 = fminf(m2, __shfl_xor(m2, 16, 64)); m2 = fminf(m2, __shfl_xor(m2, 32, 64));
    m3 = fminf(m3, __shfl_xor(m3, 16, 64)); m3 = fminf(m3, __shfl_xor(m3, 32, 64));
    if (lane < 16) {
        if (fp32mode) {
            float* C = (float*)outv + n * D + fb;
            float4 c = *(const float4*)C;
            *(float4*)C = make_float4(c.x - m0, c.y - m1, c.z - m2, c.w - m3);
        } else {
            unsigned short* C = (unsigned short*)outv + n * D + fb;
            uint2 c = *(const uint2*)C;
            unsigned lo = (unsigned)f2b(b2f((unsigned short)c.x) - m0)
                        | ((unsigned)f2b(b2f((unsigned short)(c.x >> 16)) - m1) << 16);
            unsigned hi = (unsigned)f2b(b2f((unsigned short)c.y) - m2)
                        | ((unsigned)f2b(b2f((unsigned short)(c.y >> 16)) - m3) << 16);
            *(uint2*)C = make_uint2(lo, hi);
        }
    }
}

extern "C" void kernel_launch(void* const* d_in, const int* in_sizes, int n_in,
                              void* d_out, int out_size, void* d_ws, size_t ws_size,
                              hipStream_t stream) {
    // ws layout (~11.42 MB; known-safe budget <= 12.8 MB):
    char* p = (char*)d_ws;
    unsigned*       flags   = (unsigned*)p;                      // 256 B
    unsigned*       offsets = (unsigned*)(p + 256);              // 50017*4 -> pad 200320
    unsigned*       c_cnt   = (unsigned*)(p + 256 + 200320);     // 1024
    unsigned*       c_off   = (unsigned*)(p + 256 + 201344);     // 1024
    unsigned*       c_cur   = (unsigned*)(p + 256 + 202368);     // 1024
    unsigned*       packed  = (unsigned*)(p + 256 + 203392);     // 3.2 MB
    unsigned short* esrc    = (unsigned short*)(p + 256 + 203392 + 3200000);  // 1.6 MB
    unsigned short* T16     = (unsigned short*)(p + 256 + 203392 + 3200000 + 1600000); // 6.4 MB
    unsigned short* WTfrag  = (unsigned short*)(p + 11403648);   // 8 KB (frag-ordered)
    unsigned short* WPfrag  = (unsigned short*)(p + 11411840);   // 8 KB
    float*          bias_sum= (float*)(p + 11420032);            // 256 B

    detect_mode<<<1, 128, 0, stream>>>(d_in[0], d_in[1], flags);
    prep_w<<<1, 256, 0, stream>>>(d_in[3], d_in[4], d_in[5], d_in[6], flags,
                                  WTfrag, WPfrag, bias_sum);
    node_both<<<(N_NODES / 16 + 3) / 4, 256, 0, stream>>>(d_in[0], WTfrag, WPfrag, bias_sum,
                                                          d_in[3], d_in[4], d_in[5], d_in[6],
                                                          flags, T16, d_out);
    hipMemsetAsync(c_cnt, 0, NB * sizeof(unsigned), stream);
    coarse_count<<<NPB, 256, 0, stream>>>(d_in[2], flags, c_cnt);
    scanNB<<<1, 256, 0, stream>>>(c_cnt, c_off, c_cur, offsets);
    coarse_scatter<<<NPB, 256, 0, stream>>>(d_in[1], d_in[2], flags, c_cur, packed);
    bucket_build<<<NB, 256, 0, stream>>>(c_off, packed, offsets, esrc);
    min_gather<<<N_NODES / 4, 256, 0, stream>>>(offsets, esrc, T16, flags, d_out);
}

// Round 10
// 164.215 us; speedup vs baseline: 1.2754x; 1.2754x over previous
//
#include <hip/hip_runtime.h>
#include <hip/hip_bf16.h>

#define N_NODES 50000
#define N_EDGES 800000
#define D 64
#define NB 196        // coarse buckets: dst>>8 -> 0..195
#define CHUNK_E 4096  // edges per partition block
#define NPB 196       // ceil(800000/4096)

typedef __attribute__((ext_vector_type(8))) short short8v;   // 8 bf16 (4 VGPRs)
typedef __attribute__((ext_vector_type(4))) float float4v;   // 4 fp32 acc

// ---------- helpers ----------
__device__ __forceinline__ float b2f(unsigned short h) {
    return __uint_as_float(((unsigned)h) << 16);
}
__device__ __forceinline__ unsigned short f2b(float f) {
    __hip_bfloat16 t = __float2bfloat16(f);
    return *reinterpret_cast<unsigned short*>(&t);
}
__device__ __forceinline__ short f2bs(float f) { return (short)f2b(f); }

// ---------- kernel 0: runtime dtype / index-width detection ----------
// (evidence so far: flags[0]=1 fp32 tensors, flags[1]=1 int64 indices;
//  keep detection for safety — branches are wave-uniform and cheap)
__global__ void detect_mode(const void* feat, const void* srcv, unsigned* flags) {
    const int t = threadIdx.x;          // 128 threads = 2 waves
    if (t < 64) {
        const unsigned short* p = (const unsigned short*)feat;
        float x = b2f(p[2 * t]);
        float a = fabsf(x);
        bool insane = !(a <= 64.f) || (x != 0.f && a < 9.3132e-10f);
        unsigned long long m = __ballot(insane);
        if (t == 0) flags[0] = (__popcll(m) >= 8) ? 1u : 0u;
    } else {
        const int* s32 = (const int*)srcv;
        int v = s32[2 * (t - 64) + 1];
        unsigned long long m = __ballot(v == 0);
        if (t == 64) flags[1] = (__popcll(m) >= 32) ? 1u : 0u;
    }
}

// ---------- kernel 0b: W -> bf16 W^T (fragment order), bias sums ----------
// Wfrag[n*64 + k] = bf16(W[k][n]); a B-fragment (col,h,q) is then the
// contiguous 16 bytes at element col*64 + h*32 + q*8.  (Round-9's indexing
// collided; this bijection is exact.)
__global__ __launch_bounds__(256)
void prep_w(const void* __restrict__ Wtv, const void* __restrict__ btv,
            const void* __restrict__ Wpv, const void* __restrict__ bpv,
            const unsigned* __restrict__ flags,
            unsigned short* __restrict__ WTfrag, unsigned short* __restrict__ WPfrag,
            float* __restrict__ bias_sum) {
    const unsigned fp32mode = flags[0];
    const int t = threadIdx.x;
#pragma unroll
    for (int i = 0; i < 16; ++i) {
        int e = i * 256 + t;                           // coalesced read
        int k = e >> 6, n = e & 63;
        float vt, vp;
        if (fp32mode) {
            vt = ((const float*)Wtv)[e];
            vp = ((const float*)Wpv)[e];
        } else {
            vt = b2f(((const unsigned short*)Wtv)[e]);
            vp = b2f(((const unsigned short*)Wpv)[e]);
        }
        WTfrag[n * 64 + k] = f2b(vt);
        WPfrag[n * 64 + k] = f2b(vp);
    }
    if (t < 64) {
        if (fp32mode)
            bias_sum[t] = ((const float*)btv)[t] + ((const float*)bpv)[t];
        else
            bias_sum[t] = b2f(((const unsigned short*)btv)[t])
                        + b2f(((const unsigned short*)bpv)[t]);
    }
}

// ---------- kernel 1: MFMA node transforms (both modes) ----------
// T = feat@Wt -> T16 (bf16, ws) ; C = feat@Wt + feat@Wp + bt+bp -> d_out
// fp32 mode: A converted fp32->bf16 in registers; C stored as float.
__global__ __launch_bounds__(256)
void node_both(const void* __restrict__ featv,
               const unsigned short* __restrict__ WTfrag,
               const unsigned short* __restrict__ WPfrag,
               const float* __restrict__ bias_sum,
               const unsigned* __restrict__ flags,
               unsigned short* __restrict__ T16, void* __restrict__ outv) {
    const unsigned fp32mode = flags[0];
    const int lane = threadIdx.x & 63;
    const int wid  = threadIdx.x >> 6;
    const int w = blockIdx.x * 4 + wid;                // one 16-row strip per wave
    if (w >= N_NODES / 16) return;                     // 3125 strips
    const int m = lane & 15, q = lane >> 4;

    // A frags: A[m=lane&15][k=q*8+j], two k-halves (k and k+32)
    short8v A0, A1;
    if (fp32mode) {
        const float* fr = (const float*)featv + (w * 16 + m) * D + q * 8;
        float4 l0 = *(const float4*)(fr);
        float4 h0 = *(const float4*)(fr + 4);
        float4 l1 = *(const float4*)(fr + 32);
        float4 h1 = *(const float4*)(fr + 36);
        A0 = (short8v){f2bs(l0.x), f2bs(l0.y), f2bs(l0.z), f2bs(l0.w),
                       f2bs(h0.x), f2bs(h0.y), f2bs(h0.z), f2bs(h0.w)};
        A1 = (short8v){f2bs(l1.x), f2bs(l1.y), f2bs(l1.z), f2bs(l1.w),
                       f2bs(h1.x), f2bs(h1.y), f2bs(h1.z), f2bs(h1.w)};
    } else {
        const short* fr = (const short*)featv + (w * 16 + m) * D + q * 8;
        A0 = *(const short8v*)fr;
        A1 = *(const short8v*)(fr + 32);
    }

    const short8v* BT = (const short8v*)WTfrag;        // idx = col*8 + h*4 + q
    const short8v* BP = (const short8v*)WPfrag;
    float* Cf  = (float*)outv;
    unsigned short* Ch = (unsigned short*)outv;

#pragma unroll
    for (int c = 0; c < 4; ++c) {
        const int col = 16 * c + m;
        short8v Bt0 = BT[col * 8 + q];                 // h=0
        short8v Bt1 = BT[col * 8 + 4 + q];             // h=1
        short8v Bp0 = BP[col * 8 + q];
        short8v Bp1 = BP[col * 8 + 4 + q];
        float bs = bias_sum[col];
        float4v accT = (float4v){0.f, 0.f, 0.f, 0.f};
        float4v accP = (float4v){bs, bs, bs, bs};
        accT = __builtin_amdgcn_mfma_f32_16x16x32_bf16(A0, Bt0, accT, 0, 0, 0);
        accT = __builtin_amdgcn_mfma_f32_16x16x32_bf16(A1, Bt1, accT, 0, 0, 0);
        accP = __builtin_amdgcn_mfma_f32_16x16x32_bf16(A0, Bp0, accP, 0, 0, 0);
        accP = __builtin_amdgcn_mfma_f32_16x16x32_bf16(A1, Bp1, accP, 0, 0, 0);
        // C/D layout: col = lane&15 (+16c), row = q*4 + reg
#pragma unroll
        for (int r = 0; r < 4; ++r) {
            const int row = w * 16 + q * 4 + r;
            T16[row * D + col] = f2b(accT[r]);
            if (fp32mode) Cf[row * D + col] = accT[r] + accP[r];
            else          Ch[row * D + col] = f2b(accT[r] + accP[r]);
        }
    }
}

// ---------- kernel 2: coarse bucket counts (LDS-aggregated) ----------
__global__ __launch_bounds__(256)
void coarse_count(const void* __restrict__ dstv, const unsigned* __restrict__ flags,
                  unsigned* __restrict__ c_cnt) {
    __shared__ unsigned cnt[NB];
    const int t = threadIdx.x;
    if (t < NB) cnt[t] = 0;
    __syncthreads();
    const unsigned idx64 = flags[1];
    const int base = blockIdx.x * CHUNK_E;
#pragma unroll
    for (int j = 0; j < CHUNK_E / 256; ++j) {
        int e = base + j * 256 + t;
        if (e < N_EDGES) {
            int d = idx64 ? (int)((const long long*)dstv)[e] : ((const int*)dstv)[e];
            d = min(max(d, 0), N_NODES - 1);
            atomicAdd(&cnt[d >> 8], 1u);
        }
    }
    __syncthreads();
    if (t < NB && cnt[t]) atomicAdd(&c_cnt[t], cnt[t]);
}

// ---------- kernel 3: scan of NB coarse counts -> c_off, c_cur ----------
__global__ __launch_bounds__(256)
void scanNB(const unsigned* __restrict__ c_cnt, unsigned* __restrict__ c_off,
            unsigned* __restrict__ c_cur, unsigned* __restrict__ offsets) {
    __shared__ unsigned sm[256];
    const int t = threadIdx.x;
    unsigned v = (t < NB) ? c_cnt[t] : 0u;
    sm[t] = v;
    __syncthreads();
    for (int off = 1; off < 256; off <<= 1) {
        unsigned u = (t >= off) ? sm[t - off] : 0u;
        __syncthreads();
        sm[t] += u;
        __syncthreads();
    }
    if (t < NB) { c_off[t] = sm[t] - v; c_cur[t] = sm[t] - v; }
    if (t == 0) { c_off[NB] = N_EDGES; offsets[N_NODES] = N_EDGES; }
}

// ---------- kernel 4: coarse partition of packed (dst<<16|src) ----------
__global__ __launch_bounds__(256)
void coarse_scatter(const void* __restrict__ srcv, const void* __restrict__ dstv,
                    const unsigned* __restrict__ flags,
                    unsigned* __restrict__ c_cur, unsigned* __restrict__ packed) {
    __shared__ unsigned h[NB];
    const int t = threadIdx.x;
    if (t < NB) h[t] = 0;
    __syncthreads();
    const unsigned idx64 = flags[1];
    const int base = blockIdx.x * CHUNK_E;
    unsigned pk[CHUNK_E / 256];
#pragma unroll
    for (int j = 0; j < CHUNK_E / 256; ++j) {
        int e = base + j * 256 + t;
        unsigned p = 0xFFFFFFFFu;                      // sentinel (dst<=49999 < 0xFFFF)
        if (e < N_EDGES) {
            int s, d;
            if (idx64) {
                s = (int)((const long long*)srcv)[e];
                d = (int)((const long long*)dstv)[e];
            } else {
                s = ((const int*)srcv)[e];
                d = ((const int*)dstv)[e];
            }
            s = min(max(s, 0), N_NODES - 1);
            d = min(max(d, 0), N_NODES - 1);
            p = ((unsigned)d << 16) | (unsigned)s;
            atomicAdd(&h[d >> 8], 1u);
        }
        pk[j] = p;
    }
    __syncthreads();
    // one reservation atomic per (block,bucket); h becomes the LDS write cursor
    if (t < NB) h[t] = atomicAdd(&c_cur[t], h[t]);
    __syncthreads();
#pragma unroll
    for (int j = 0; j < CHUNK_E / 256; ++j) {
        unsigned p = pk[j];
        if (p != 0xFFFFFFFFu) {
            unsigned pos = atomicAdd(&h[p >> 24], 1u); // p>>24 == dst>>8
            packed[pos] = p;
        }
    }
}

// ---------- kernel 5: per-bucket node hist + scan + fine scatter (all LDS) ----------
__global__ __launch_bounds__(256)
void bucket_build(const unsigned* __restrict__ c_off, const unsigned* __restrict__ packed,
                  unsigned* __restrict__ offsets, unsigned short* __restrict__ esrc) {
    __shared__ unsigned h[256];   // node counts -> node cursors
    __shared__ unsigned s[256];   // scan buffer
    const int t = threadIdx.x;
    const int b = blockIdx.x;
    const int estart = (int)c_off[b];
    const int eend   = (int)c_off[b + 1];
    h[t] = 0;
    __syncthreads();
    for (int i = estart + t; i < eend; i += 256)
        atomicAdd(&h[(packed[i] >> 16) & 255], 1u);
    __syncthreads();
    unsigned c = h[t];
    s[t] = c;
    __syncthreads();
    for (int off = 1; off < 256; off <<= 1) {
        unsigned u = (t >= off) ? s[t - off] : 0u;
        __syncthreads();
        s[t] += u;
        __syncthreads();
    }
    unsigned pos0 = (unsigned)estart + s[t] - c;       // CSR start for this node
    h[t] = pos0;                                       // own slot only
    const int node = (b << 8) + t;
    if (node < N_NODES) offsets[node] = pos0;
    __syncthreads();
    for (int i = estart + t; i < eend; i += 256) {
        unsigned p = packed[i];
        unsigned pos = atomicAdd(&h[(p >> 16) & 255], 1u);
        esrc[pos] = (unsigned short)(p & 0xFFFFu);
    }
}

// ---------- kernel 6: per-node segmented min + fused epilogue ----------
// lane = (edge-group g = lane>>4, feature-quad fb = (lane&15)*4)
// out[n] = C[n] - min ; C read from d_out, overwritten in place (own row only)
__global__ __launch_bounds__(256)
void min_gather(const unsigned* __restrict__ offsets, const unsigned short* __restrict__ esrc,
                const unsigned short* __restrict__ T16, const unsigned* __restrict__ flags,
                void* __restrict__ outv) {
    const unsigned fp32mode = flags[0];
    const int lane = threadIdx.x & 63;
    const int wid  = threadIdx.x >> 6;
    const int n = (blockIdx.x << 2) + wid;             // grid exact: 12500*4 waves
    const int g  = lane >> 4;
    const int fb = (lane & 15) << 2;
    const int a = (int)offsets[n];
    const int b = (int)offsets[n + 1];
    const float FMAX = __uint_as_float(0x7f7fffffu);
    float m0 = FMAX, m1 = FMAX, m2 = FMAX, m3 = FMAX;

    int i = a + g;
    for (; i + 4 < b; i += 8) {                        // 2 gathers in flight
        int s0 = (int)esrc[i], s1 = (int)esrc[i + 4];
        uint2 v0 = *(const uint2*)(T16 + s0 * D + fb);
        uint2 v1 = *(const uint2*)(T16 + s1 * D + fb);
        m0 = fminf(m0, fminf(b2f((unsigned short)v0.x), b2f((unsigned short)v1.x)));
        m1 = fminf(m1, fminf(b2f((unsigned short)(v0.x >> 16)), b2f((unsigned short)(v1.x >> 16))));
        m2 = fminf(m2, fminf(b2f((unsigned short)v0.y), b2f((unsigned short)v1.y)));
        m3 = fminf(m3, fminf(b2f((unsigned short)(v0.y >> 16)), b2f((unsigned short)(v1.y >> 16))));
    }
    if (i < b) {
        int s0 = (int)esrc[i];
        uint2 v0 = *(const uint2*)(T16 + s0 * D + fb);
        m0 = fminf(m0, b2f((unsigned short)v0.x));
        m1 = fminf(m1, b2f((unsigned short)(v0.x >> 16)));
        m2 = fminf(m2, b2f((unsigned short)v0.y));
        m3 = fminf(m3, b2f((unsigned short)(v0.y >> 16)));
    }
    // combine the 4 edge-groups: lanes l, l^16, l^32, l^48 share features
    m0 = fminf(m0, __shfl_xor(m0, 16, 64)); m0 = fminf(m0, __shfl_xor(m0, 32, 64));
    m1 = fminf(m1, __shfl_xor(m1, 16, 64)); m1 = fminf(m1, __shfl_xor(m1, 32, 64));
    m2 = fminf(m2, __shfl_xor(m2, 16, 64)); m2 = fminf(m2, __shfl_xor(m2, 32, 64));
    m3 = fminf(m3, __shfl_xor(m3, 16, 64)); m3 = fminf(m3, __shfl_xor(m3, 32, 64));
    if (lane < 16) {
        if (fp32mode) {
            float* C = (float*)outv + n * D + fb;
            float4 c = *(const float4*)C;
            *(float4*)C = make_float4(c.x - m0, c.y - m1, c.z - m2, c.w - m3);
        } else {
            unsigned short* C = (unsigned short*)outv + n * D + fb;
            uint2 c = *(const uint2*)C;
            unsigned lo = (unsigned)f2b(b2f((unsigned short)c.x) - m0)
                        | ((unsigned)f2b(b2f((unsigned short)(c.x >> 16)) - m1) << 16);
            unsigned hi = (unsigned)f2b(b2f((unsigned short)c.y) - m2)
                        | ((unsigned)f2b(b2f((unsigned short)(c.y >> 16)) - m3) << 16);
            *(uint2*)C = make_uint2(lo, hi);
        }
    }
}

extern "C" void kernel_launch(void* const* d_in, const int* in_sizes, int n_in,
                              void* d_out, int out_size, void* d_ws, size_t ws_size,
                              hipStream_t stream) {
    // ws layout (~11.42 MB; known-safe budget <= 12.8 MB):
    char* p = (char*)d_ws;
    unsigned*       flags   = (unsigned*)p;                      // 256 B
    unsigned*       offsets = (unsigned*)(p + 256);              // 50017*4 -> pad 200320
    unsigned*       c_cnt   = (unsigned*)(p + 256 + 200320);     // 1024
    unsigned*       c_off   = (unsigned*)(p + 256 + 201344);     // 1024
    unsigned*       c_cur   = (unsigned*)(p + 256 + 202368);     // 1024
    unsigned*       packed  = (unsigned*)(p + 256 + 203392);     // 3.2 MB
    unsigned short* esrc    = (unsigned short*)(p + 256 + 203392 + 3200000);  // 1.6 MB
    unsigned short* T16     = (unsigned short*)(p + 256 + 203392 + 3200000 + 1600000); // 6.4 MB
    unsigned short* WTfrag  = (unsigned short*)(p + 11403648);   // 8 KB (bf16 W^T)
    unsigned short* WPfrag  = (unsigned short*)(p + 11411840);   // 8 KB
    float*          bias_sum= (float*)(p + 11420032);            // 256 B

    detect_mode<<<1, 128, 0, stream>>>(d_in[0], d_in[1], flags);
    prep_w<<<1, 256, 0, stream>>>(d_in[3], d_in[4], d_in[5], d_in[6], flags,
                                  WTfrag, WPfrag, bias_sum);
    node_both<<<(N_NODES / 16 + 3) / 4, 256, 0, stream>>>(d_in[0], WTfrag, WPfrag, bias_sum,
                                                          flags, T16, d_out);
    hipMemsetAsync(c_cnt, 0, NB * sizeof(unsigned), stream);
    coarse_count<<<NPB, 256, 0, stream>>>(d_in[2], flags, c_cnt);
    scanNB<<<1, 256, 0, stream>>>(c_cnt, c_off, c_cur, offsets);
    coarse_scatter<<<NPB, 256, 0, stream>>>(d_in[1], d_in[2], flags, c_cur, packed);
    bucket_build<<<NB, 256, 0, stream>>>(c_off, packed, offsets, esrc);
    min_gather<<<N_NODES / 4, 256, 0, stream>>>(offsets, esrc, T16, flags, d_out);
}

// Round 11
// 155.665 us; speedup vs baseline: 1.3455x; 1.0549x over previous
//
#include <hip/hip_runtime.h>
#include <hip/hip_bf16.h>

#define N_NODES 50000
#define N_EDGES 800000
#define D 64
#define NB 196        // coarse buckets: dst>>8 -> 0..195
#define CHUNK_E 2048  // edges per partition block
#define NPB 391       // ceil(800000/2048)
#define NSTRIP 3125   // N_NODES/16
#define GEMM_BLKS 782 // ceil(3125/4)

typedef __attribute__((ext_vector_type(8))) short short8v;   // 8 bf16 (4 VGPRs)
typedef __attribute__((ext_vector_type(4))) float float4v;   // 4 fp32 acc

// ---------- helpers ----------
__device__ __forceinline__ float b2f(unsigned short h) {
    return __uint_as_float(((unsigned)h) << 16);
}
__device__ __forceinline__ unsigned short f2b(float f) {
    __hip_bfloat16 t = __float2bfloat16(f);
    return *reinterpret_cast<unsigned short*>(&t);
}
__device__ __forceinline__ short f2bs(float f) { return (short)f2b(f); }

// ---------- kernel 1: setup = detect + prep_w + zero c_cnt (1 block) ----------
// Wfrag[n*64 + k] = bf16(W[k][n]); B-fragment (col,h,q) = contiguous 16 B at
// element col*64 + h*32 + q*8.
__global__ __launch_bounds__(256)
void setup(const void* __restrict__ featv, const void* __restrict__ srcv,
           const void* __restrict__ Wtv, const void* __restrict__ btv,
           const void* __restrict__ Wpv, const void* __restrict__ bpv,
           unsigned* __restrict__ flags, unsigned* __restrict__ c_cnt,
           unsigned short* __restrict__ WTfrag, unsigned short* __restrict__ WPfrag,
           float* __restrict__ bias_sum) {
    __shared__ unsigned sf[2];
    const int t = threadIdx.x;
    if (t < 64) {
        // fp32-vs-bf16 probe: even bf16 halves of an fp32 buffer are garbage
        const unsigned short* p = (const unsigned short*)featv;
        float x = b2f(p[2 * t]);
        float a = fabsf(x);
        bool insane = !(a <= 64.f) || (x != 0.f && a < 9.3132e-10f);
        unsigned long long m = __ballot(insane);
        if (t == 0) sf[0] = (__popcll(m) >= 8) ? 1u : 0u;
    } else if (t < 128) {
        // int64 probe: odd int32 words all-zero <=> int64 indices
        const int* s32 = (const int*)srcv;
        int v = s32[2 * (t - 64) + 1];
        unsigned long long m = __ballot(v == 0);
        if (t == 64) sf[1] = (__popcll(m) >= 32) ? 1u : 0u;
    }
    __syncthreads();
    const unsigned fp32mode = sf[0];
    if (t < 2) flags[t] = sf[t];
    if (t < NB) c_cnt[t] = 0;
#pragma unroll
    for (int i = 0; i < 16; ++i) {
        int e = i * 256 + t;                           // coalesced read
        int k = e >> 6, n = e & 63;
        float vt, vp;
        if (fp32mode) {
            vt = ((const float*)Wtv)[e];
            vp = ((const float*)Wpv)[e];
        } else {
            vt = b2f(((const unsigned short*)Wtv)[e]);
            vp = b2f(((const unsigned short*)Wpv)[e]);
        }
        WTfrag[n * 64 + k] = f2b(vt);
        WPfrag[n * 64 + k] = f2b(vp);
    }
    if (t < 64) {
        if (fp32mode)
            bias_sum[t] = ((const float*)btv)[t] + ((const float*)bpv)[t];
        else
            bias_sum[t] = b2f(((const unsigned short*)btv)[t])
                        + b2f(((const unsigned short*)bpv)[t]);
    }
}

// ---------- kernel 2: fused [MFMA node transforms | coarse dst histogram] ----
// blocks [0, GEMM_BLKS): T = feat@Wt -> T16 ; C = feat@(Wt+Wp)+b -> d_out
// blocks [GEMM_BLKS, GEMM_BLKS+NPB): LDS histogram of dst>>8 -> c_cnt
__global__ __launch_bounds__(256)
void gemm_count(const void* __restrict__ featv,
                const unsigned short* __restrict__ WTfrag,
                const unsigned short* __restrict__ WPfrag,
                const float* __restrict__ bias_sum,
                const void* __restrict__ dstv,
                const unsigned* __restrict__ flags,
                unsigned* __restrict__ c_cnt,
                unsigned short* __restrict__ T16, void* __restrict__ outv) {
    const unsigned fp32mode = flags[0];
    if (blockIdx.x < GEMM_BLKS) {
        const int lane = threadIdx.x & 63;
        const int wid  = threadIdx.x >> 6;
        const int w = blockIdx.x * 4 + wid;            // one 16-row strip per wave
        if (w >= NSTRIP) return;
        const int m = lane & 15, q = lane >> 4;

        // A frags: A[m=lane&15][k=q*8+j], two k-halves (k and k+32)
        short8v A0, A1;
        if (fp32mode) {
            const float* fr = (const float*)featv + (w * 16 + m) * D + q * 8;
            float4 l0 = *(const float4*)(fr);
            float4 h0 = *(const float4*)(fr + 4);
            float4 l1 = *(const float4*)(fr + 32);
            float4 h1 = *(const float4*)(fr + 36);
            A0 = (short8v){f2bs(l0.x), f2bs(l0.y), f2bs(l0.z), f2bs(l0.w),
                           f2bs(h0.x), f2bs(h0.y), f2bs(h0.z), f2bs(h0.w)};
            A1 = (short8v){f2bs(l1.x), f2bs(l1.y), f2bs(l1.z), f2bs(l1.w),
                           f2bs(h1.x), f2bs(h1.y), f2bs(h1.z), f2bs(h1.w)};
        } else {
            const short* fr = (const short*)featv + (w * 16 + m) * D + q * 8;
            A0 = *(const short8v*)fr;
            A1 = *(const short8v*)(fr + 32);
        }

        const short8v* BT = (const short8v*)WTfrag;    // idx = col*8 + h*4 + q
        const short8v* BP = (const short8v*)WPfrag;
        float* Cf  = (float*)outv;
        unsigned short* Ch = (unsigned short*)outv;

#pragma unroll
        for (int c = 0; c < 4; ++c) {
            const int col = 16 * c + m;
            short8v Bt0 = BT[col * 8 + q];             // h=0
            short8v Bt1 = BT[col * 8 + 4 + q];         // h=1
            short8v Bp0 = BP[col * 8 + q];
            short8v Bp1 = BP[col * 8 + 4 + q];
            float bs = bias_sum[col];
            float4v accT = (float4v){0.f, 0.f, 0.f, 0.f};
            float4v accP = (float4v){bs, bs, bs, bs};
            accT = __builtin_amdgcn_mfma_f32_16x16x32_bf16(A0, Bt0, accT, 0, 0, 0);
            accT = __builtin_amdgcn_mfma_f32_16x16x32_bf16(A1, Bt1, accT, 0, 0, 0);
            accP = __builtin_amdgcn_mfma_f32_16x16x32_bf16(A0, Bp0, accP, 0, 0, 0);
            accP = __builtin_amdgcn_mfma_f32_16x16x32_bf16(A1, Bp1, accP, 0, 0, 0);
            // C/D layout: col = lane&15 (+16c), row = q*4 + reg
#pragma unroll
            for (int r = 0; r < 4; ++r) {
                const int row = w * 16 + q * 4 + r;
                T16[row * D + col] = f2b(accT[r]);
                if (fp32mode) Cf[row * D + col] = accT[r] + accP[r];
                else          Ch[row * D + col] = f2b(accT[r] + accP[r]);
            }
        }
    } else {
        // ---- coarse histogram branch ----
        __shared__ unsigned cnt[NB];
        const int t = threadIdx.x;
        if (t < NB) cnt[t] = 0;
        __syncthreads();
        const unsigned idx64 = flags[1];
        const int base = (blockIdx.x - GEMM_BLKS) * CHUNK_E;
#pragma unroll
        for (int j = 0; j < CHUNK_E / 256; ++j) {
            int e = base + j * 256 + t;
            if (e < N_EDGES) {
                int d = idx64 ? (int)((const long long*)dstv)[e] : ((const int*)dstv)[e];
                d = min(max(d, 0), N_NODES - 1);
                atomicAdd(&cnt[d >> 8], 1u);
            }
        }
        __syncthreads();
        if (t < NB && cnt[t]) atomicAdd(&c_cnt[t], cnt[t]);
    }
}

// ---------- kernel 3: scan of NB coarse counts -> c_off, c_cur ----------
__global__ __launch_bounds__(256)
void scanNB(const unsigned* __restrict__ c_cnt, unsigned* __restrict__ c_off,
            unsigned* __restrict__ c_cur, unsigned* __restrict__ offsets) {
    __shared__ unsigned sm[256];
    const int t = threadIdx.x;
    unsigned v = (t < NB) ? c_cnt[t] : 0u;
    sm[t] = v;
    __syncthreads();
    for (int off = 1; off < 256; off <<= 1) {
        unsigned u = (t >= off) ? sm[t - off] : 0u;
        __syncthreads();
        sm[t] += u;
        __syncthreads();
    }
    if (t < NB) { c_off[t] = sm[t] - v; c_cur[t] = sm[t] - v; }
    if (t == 0) { c_off[NB] = N_EDGES; offsets[N_NODES] = N_EDGES; }
}

// ---------- kernel 4: coarse partition of packed (dst<<16|src) ----------
__global__ __launch_bounds__(256)
void coarse_scatter(const void* __restrict__ srcv, const void* __restrict__ dstv,
                    const unsigned* __restrict__ flags,
                    unsigned* __restrict__ c_cur, unsigned* __restrict__ packed) {
    __shared__ unsigned h[NB];
    const int t = threadIdx.x;
    if (t < NB) h[t] = 0;
    __syncthreads();
    const unsigned idx64 = flags[1];
    const int base = blockIdx.x * CHUNK_E;
    unsigned pk[CHUNK_E / 256];
#pragma unroll
    for (int j = 0; j < CHUNK_E / 256; ++j) {
        int e = base + j * 256 + t;
        unsigned p = 0xFFFFFFFFu;                      // sentinel
        if (e < N_EDGES) {
            int s, d;
            if (idx64) {
                s = (int)((const long long*)srcv)[e];
                d = (int)((const long long*)dstv)[e];
            } else {
                s = ((const int*)srcv)[e];
                d = ((const int*)dstv)[e];
            }
            s = min(max(s, 0), N_NODES - 1);
            d = min(max(d, 0), N_NODES - 1);
            p = ((unsigned)d << 16) | (unsigned)s;
            atomicAdd(&h[d >> 8], 1u);
        }
        pk[j] = p;
    }
    __syncthreads();
    // one reservation atomic per (block,bucket); h becomes the LDS write cursor
    if (t < NB) h[t] = atomicAdd(&c_cur[t], h[t]);
    __syncthreads();
#pragma unroll
    for (int j = 0; j < CHUNK_E / 256; ++j) {
        unsigned p = pk[j];
        if (p != 0xFFFFFFFFu) {
            unsigned pos = atomicAdd(&h[p >> 24], 1u); // p>>24 == dst>>8
            packed[pos] = p;
        }
    }
}

// ---------- kernel 5: per-bucket node hist + scan + fine scatter (all LDS) ----------
__global__ __launch_bounds__(512)
void bucket_build(const unsigned* __restrict__ c_off, const unsigned* __restrict__ packed,
                  unsigned* __restrict__ offsets, unsigned short* __restrict__ esrc) {
    __shared__ unsigned h[256];   // node counts -> node cursors
    __shared__ unsigned s[256];   // scan buffer
    const int t = threadIdx.x;
    const int b = blockIdx.x;
    const int estart = (int)c_off[b];
    const int eend   = (int)c_off[b + 1];
    if (t < 256) h[t] = 0;
    __syncthreads();
    for (int i = estart + t; i < eend; i += 512)
        atomicAdd(&h[(packed[i] >> 16) & 255], 1u);
    __syncthreads();
    unsigned c = 0;
    if (t < 256) { c = h[t]; s[t] = c; }
    __syncthreads();
    for (int off = 1; off < 256; off <<= 1) {
        unsigned u = (t >= off && t < 256) ? s[t - off] : 0u;
        __syncthreads();
        if (t < 256) s[t] += u;
        __syncthreads();
    }
    if (t < 256) {
        unsigned pos0 = (unsigned)estart + s[t] - c;   // CSR start for this node
        h[t] = pos0;                                   // own slot only
        const int node = (b << 8) + t;
        if (node < N_NODES) offsets[node] = pos0;
    }
    __syncthreads();
    for (int i = estart + t; i < eend; i += 512) {
        unsigned p = packed[i];
        unsigned pos = atomicAdd(&h[(p >> 16) & 255], 1u);
        esrc[pos] = (unsigned short)(p & 0xFFFFu);
    }
}

// ---------- kernel 6: per-node segmented min + fused epilogue ----------
// lane = (edge-group g = lane>>4, feature-quad fb = (lane&15)*4)
// out[n] = C[n] - min ; C read from d_out, overwritten in place (own row only)
__global__ __launch_bounds__(256)
void min_gather(const unsigned* __restrict__ offsets, const unsigned short* __restrict__ esrc,
                const unsigned short* __restrict__ T16, const unsigned* __restrict__ flags,
                void* __restrict__ outv) {
    const unsigned fp32mode = flags[0];
    const int lane = threadIdx.x & 63;
    const int wid  = threadIdx.x >> 6;
    const int n = (blockIdx.x << 2) + wid;             // grid exact: 12500*4 waves
    const int g  = lane >> 4;
    const int fb = (lane & 15) << 2;
    const int a = (int)offsets[n];
    const int b = (int)offsets[n + 1];
    const float FMAX = __uint_as_float(0x7f7fffffu);
    float m0 = FMAX, m1 = FMAX, m2 = FMAX, m3 = FMAX;

    int i = a + g;
    for (; i + 12 < b; i += 16) {                      // 4 gathers in flight
        int s0 = (int)esrc[i],     s1 = (int)esrc[i + 4];
        int s2 = (int)esrc[i + 8], s3 = (int)esrc[i + 12];
        uint2 v0 = *(const uint2*)(T16 + s0 * D + fb);
        uint2 v1 = *(const uint2*)(T16 + s1 * D + fb);
        uint2 v2 = *(const uint2*)(T16 + s2 * D + fb);
        uint2 v3 = *(const uint2*)(T16 + s3 * D + fb);
        m0 = fminf(fminf(m0, fminf(b2f((unsigned short)v0.x), b2f((unsigned short)v1.x))),
                   fminf(b2f((unsigned short)v2.x), b2f((unsigned short)v3.x)));
        m1 = fminf(fminf(m1, fminf(b2f((unsigned short)(v0.x >> 16)), b2f((unsigned short)(v1.x >> 16)))),
                   fminf(b2f((unsigned short)(v2.x >> 16)), b2f((unsigned short)(v3.x >> 16))));
        m2 = fminf(fminf(m2, fminf(b2f((unsigned short)v0.y), b2f((unsigned short)v1.y))),
                   fminf(b2f((unsigned short)v2.y), b2f((unsigned short)v3.y)));
        m3 = fminf(fminf(m3, fminf(b2f((unsigned short)(v0.y >> 16)), b2f((unsigned short)(v1.y >> 16)))),
                   fminf(b2f((unsigned short)(v2.y >> 16)), b2f((unsigned short)(v3.y >> 16))));
    }
    for (; i < b; i += 4) {
        int s0 = (int)esrc[i];
        uint2 v0 = *(const uint2*)(T16 + s0 * D + fb);
        m0 = fminf(m0, b2f((unsigned short)v0.x));
        m1 = fminf(m1, b2f((unsigned short)(v0.x >> 16)));
        m2 = fminf(m2, b2f((unsigned short)v0.y));
        m3 = fminf(m3, b2f((unsigned short)(v0.y >> 16)));
    }
    // combine the 4 edge-groups: lanes l, l^16, l^32, l^48 share features
    m0 = fminf(m0, __shfl_xor(m0, 16, 64)); m0 = fminf(m0, __shfl_xor(m0, 32, 64));
    m1 = fminf(m1, __shfl_xor(m1, 16, 64)); m1 = fminf(m1, __shfl_xor(m1, 32, 64));
    m2 = fminf(m2, __shfl_xor(m2, 16, 64)); m2 = fminf(m2, __shfl_xor(m2, 32, 64));
    m3 = fminf(m3, __shfl_xor(m3, 16, 64)); m3 = fminf(m3, __shfl_xor(m3, 32, 64));
    if (lane < 16) {
        if (fp32mode) {
            float* C = (float*)outv + n * D + fb;
            float4 c = *(const float4*)C;
            *(float4*)C = make_float4(c.x - m0, c.y - m1, c.z - m2, c.w - m3);
        } else {
            unsigned short* C = (unsigned short*)outv + n * D + fb;
            uint2 c = *(const uint2*)C;
            unsigned lo = (unsigned)f2b(b2f((unsigned short)c.x) - m0)
                        | ((unsigned)f2b(b2f((unsigned short)(c.x >> 16)) - m1) << 16);
            unsigned hi = (unsigned)f2b(b2f((unsigned short)c.y) - m2)
                        | ((unsigned)f2b(b2f((unsigned short)(c.y >> 16)) - m3) << 16);
            *(uint2*)C = make_uint2(lo, hi);
        }
    }
}

extern "C" void kernel_launch(void* const* d_in, const int* in_sizes, int n_in,
                              void* d_out, int out_size, void* d_ws, size_t ws_size,
                              hipStream_t stream) {
    // ws layout (~11.42 MB used; ws is much larger — fill shows ~256 MB):
    char* p = (char*)d_ws;
    unsigned*       flags   = (unsigned*)p;                      // 256 B
    unsigned*       offsets = (unsigned*)(p + 256);              // 50017*4 -> pad 200320
    unsigned*       c_cnt   = (unsigned*)(p + 256 + 200320);     // 1024
    unsigned*       c_off   = (unsigned*)(p + 256 + 201344);     // 1024
    unsigned*       c_cur   = (unsigned*)(p + 256 + 202368);     // 1024
    unsigned*       packed  = (unsigned*)(p + 256 + 203392);     // 3.2 MB
    unsigned short* esrc    = (unsigned short*)(p + 256 + 203392 + 3200000);  // 1.6 MB
    unsigned short* T16     = (unsigned short*)(p + 256 + 203392 + 3200000 + 1600000); // 6.4 MB
    unsigned short* WTfrag  = (unsigned short*)(p + 11403648);   // 8 KB (bf16 W^T)
    unsigned short* WPfrag  = (unsigned short*)(p + 11411840);   // 8 KB
    float*          bias_sum= (float*)(p + 11420032);            // 256 B

    setup<<<1, 256, 0, stream>>>(d_in[0], d_in[1], d_in[3], d_in[4], d_in[5], d_in[6],
                                 flags, c_cnt, WTfrag, WPfrag, bias_sum);
    gemm_count<<<GEMM_BLKS + NPB, 256, 0, stream>>>(d_in[0], WTfrag, WPfrag, bias_sum,
                                                    d_in[2], flags, c_cnt, T16, d_out);
    scanNB<<<1, 256, 0, stream>>>(c_cnt, c_off, c_cur, offsets);
    coarse_scatter<<<NPB, 256, 0, stream>>>(d_in[1], d_in[2], flags, c_cur, packed);
    bucket_build<<<NB, 512, 0, stream>>>(c_off, packed, offsets, esrc);
    min_gather<<<N_NODES / 4, 256, 0, stream>>>(offsets, esrc, T16, flags, d_out);
}

// Round 12
// 153.758 us; speedup vs baseline: 1.3622x; 1.0124x over previous
//
#include <hip/hip_runtime.h>
#include <hip/hip_bf16.h>

#define N_NODES 50000
#define N_EDGES 800000
#define D 64
#define NB 391        // coarse buckets: dst>>7 -> 0..390 (128 nodes/bucket)
#define CHUNK_E 2048  // edges per partition block
#define NPB 391       // ceil(800000/2048)
#define NSTRIP 3125   // N_NODES/16
#define GEMM_BLKS 782 // ceil(3125/4)

typedef __attribute__((ext_vector_type(8))) short short8v;   // 8 bf16 (4 VGPRs)
typedef __attribute__((ext_vector_type(4))) float float4v;   // 4 fp32 acc

// ---------- helpers ----------
__device__ __forceinline__ float b2f(unsigned short h) {
    return __uint_as_float(((unsigned)h) << 16);
}
__device__ __forceinline__ unsigned short f2b(float f) {
    __hip_bfloat16 t = __float2bfloat16(f);
    return *reinterpret_cast<unsigned short*>(&t);
}
__device__ __forceinline__ short f2bs(float f) { return (short)f2b(f); }
// monotonic float<->uint encoding: unsigned min == float min
__device__ __forceinline__ unsigned f2ord(float f) {
    unsigned u = __float_as_uint(f);
    return (u & 0x80000000u) ? ~u : (u | 0x80000000u);
}
__device__ __forceinline__ float ord2f(unsigned o) {
    return __uint_as_float((o & 0x80000000u) ? (o ^ 0x80000000u) : ~o);
}

// ---------- kernel 1: setup = detect + prep_w + zero c_cnt (1 block) ----------
// Wfrag[n*64 + k] = bf16(W[k][n]); B-fragment (col,h,q) = contiguous 16 B at
// element col*64 + h*32 + q*8.
__global__ __launch_bounds__(256)
void setup(const void* __restrict__ featv, const void* __restrict__ srcv,
           const void* __restrict__ Wtv, const void* __restrict__ btv,
           const void* __restrict__ Wpv, const void* __restrict__ bpv,
           unsigned* __restrict__ flags, unsigned* __restrict__ c_cnt,
           unsigned short* __restrict__ WTfrag, unsigned short* __restrict__ WPfrag,
           float* __restrict__ bias_sum) {
    __shared__ unsigned sf[2];
    const int t = threadIdx.x;
    if (t < 64) {
        // fp32-vs-bf16 probe: even bf16 halves of an fp32 buffer are garbage
        const unsigned short* p = (const unsigned short*)featv;
        float x = b2f(p[2 * t]);
        float a = fabsf(x);
        bool insane = !(a <= 64.f) || (x != 0.f && a < 9.3132e-10f);
        unsigned long long m = __ballot(insane);
        if (t == 0) sf[0] = (__popcll(m) >= 8) ? 1u : 0u;
    } else if (t < 128) {
        // int64 probe: odd int32 words all-zero <=> int64 indices
        const int* s32 = (const int*)srcv;
        int v = s32[2 * (t - 64) + 1];
        unsigned long long m = __ballot(v == 0);
        if (t == 64) sf[1] = (__popcll(m) >= 32) ? 1u : 0u;
    }
    __syncthreads();
    const unsigned fp32mode = sf[0];
    if (t < 2) flags[t] = sf[t];
    for (int i = t; i < NB; i += 256) c_cnt[i] = 0;
#pragma unroll
    for (int i = 0; i < 16; ++i) {
        int e = i * 256 + t;                           // coalesced read
        int k = e >> 6, n = e & 63;
        float vt, vp;
        if (fp32mode) {
            vt = ((const float*)Wtv)[e];
            vp = ((const float*)Wpv)[e];
        } else {
            vt = b2f(((const unsigned short*)Wtv)[e]);
            vp = b2f(((const unsigned short*)Wpv)[e]);
        }
        WTfrag[n * 64 + k] = f2b(vt);
        WPfrag[n * 64 + k] = f2b(vp);
    }
    if (t < 64) {
        if (fp32mode)
            bias_sum[t] = ((const float*)btv)[t] + ((const float*)bpv)[t];
        else
            bias_sum[t] = b2f(((const unsigned short*)btv)[t])
                        + b2f(((const unsigned short*)bpv)[t]);
    }
}

// ---------- kernel 2: fused [MFMA node transforms | coarse dst histogram] ----
__global__ __launch_bounds__(256)
void gemm_count(const void* __restrict__ featv,
                const unsigned short* __restrict__ WTfrag,
                const unsigned short* __restrict__ WPfrag,
                const float* __restrict__ bias_sum,
                const void* __restrict__ dstv,
                const unsigned* __restrict__ flags,
                unsigned* __restrict__ c_cnt,
                unsigned short* __restrict__ T16, void* __restrict__ outv) {
    const unsigned fp32mode = flags[0];
    if (blockIdx.x < GEMM_BLKS) {
        const int lane = threadIdx.x & 63;
        const int wid  = threadIdx.x >> 6;
        const int w = blockIdx.x * 4 + wid;            // one 16-row strip per wave
        if (w >= NSTRIP) return;
        const int m = lane & 15, q = lane >> 4;

        short8v A0, A1;
        if (fp32mode) {
            const float* fr = (const float*)featv + (w * 16 + m) * D + q * 8;
            float4 l0 = *(const float4*)(fr);
            float4 h0 = *(const float4*)(fr + 4);
            float4 l1 = *(const float4*)(fr + 32);
            float4 h1 = *(const float4*)(fr + 36);
            A0 = (short8v){f2bs(l0.x), f2bs(l0.y), f2bs(l0.z), f2bs(l0.w),
                           f2bs(h0.x), f2bs(h0.y), f2bs(h0.z), f2bs(h0.w)};
            A1 = (short8v){f2bs(l1.x), f2bs(l1.y), f2bs(l1.z), f2bs(l1.w),
                           f2bs(h1.x), f2bs(h1.y), f2bs(h1.z), f2bs(h1.w)};
        } else {
            const short* fr = (const short*)featv + (w * 16 + m) * D + q * 8;
            A0 = *(const short8v*)fr;
            A1 = *(const short8v*)(fr + 32);
        }

        const short8v* BT = (const short8v*)WTfrag;    // idx = col*8 + h*4 + q
        const short8v* BP = (const short8v*)WPfrag;
        float* Cf  = (float*)outv;
        unsigned short* Ch = (unsigned short*)outv;

#pragma unroll
        for (int c = 0; c < 4; ++c) {
            const int col = 16 * c + m;
            short8v Bt0 = BT[col * 8 + q];
            short8v Bt1 = BT[col * 8 + 4 + q];
            short8v Bp0 = BP[col * 8 + q];
            short8v Bp1 = BP[col * 8 + 4 + q];
            float bs = bias_sum[col];
            float4v accT = (float4v){0.f, 0.f, 0.f, 0.f};
            float4v accP = (float4v){bs, bs, bs, bs};
            accT = __builtin_amdgcn_mfma_f32_16x16x32_bf16(A0, Bt0, accT, 0, 0, 0);
            accT = __builtin_amdgcn_mfma_f32_16x16x32_bf16(A1, Bt1, accT, 0, 0, 0);
            accP = __builtin_amdgcn_mfma_f32_16x16x32_bf16(A0, Bp0, accP, 0, 0, 0);
            accP = __builtin_amdgcn_mfma_f32_16x16x32_bf16(A1, Bp1, accP, 0, 0, 0);
            // C/D layout: col = lane&15 (+16c), row = q*4 + reg
#pragma unroll
            for (int r = 0; r < 4; ++r) {
                const int row = w * 16 + q * 4 + r;
                T16[row * D + col] = f2b(accT[r]);
                if (fp32mode) Cf[row * D + col] = accT[r] + accP[r];
                else          Ch[row * D + col] = f2b(accT[r] + accP[r]);
            }
        }
    } else {
        // ---- coarse histogram branch (dst>>7) ----
        __shared__ unsigned cnt[NB];
        const int t = threadIdx.x;
        for (int i = t; i < NB; i += 256) cnt[i] = 0;
        __syncthreads();
        const unsigned idx64 = flags[1];
        const int base = (blockIdx.x - GEMM_BLKS) * CHUNK_E;
#pragma unroll
        for (int j = 0; j < CHUNK_E / 256; ++j) {
            int e = base + j * 256 + t;
            if (e < N_EDGES) {
                int d = idx64 ? (int)((const long long*)dstv)[e] : ((const int*)dstv)[e];
                d = min(max(d, 0), N_NODES - 1);
                atomicAdd(&cnt[d >> 7], 1u);
            }
        }
        __syncthreads();
        for (int i = t; i < NB; i += 256)
            if (cnt[i]) atomicAdd(&c_cnt[i], cnt[i]);
    }
}

// ---------- kernel 3: scan of NB coarse counts -> c_off, c_cur ----------
__global__ __launch_bounds__(512)
void scanNB(const unsigned* __restrict__ c_cnt, unsigned* __restrict__ c_off,
            unsigned* __restrict__ c_cur) {
    __shared__ unsigned sm[512];
    const int t = threadIdx.x;
    unsigned v = (t < NB) ? c_cnt[t] : 0u;
    sm[t] = v;
    __syncthreads();
    for (int off = 1; off < 512; off <<= 1) {
        unsigned u = (t >= off) ? sm[t - off] : 0u;
        __syncthreads();
        sm[t] += u;
        __syncthreads();
    }
    if (t < NB) { c_off[t] = sm[t] - v; c_cur[t] = sm[t] - v; }
    if (t == 0) c_off[NB] = N_EDGES;
}

// ---------- kernel 4: coarse partition of packed (dst<<16|src) ----------
__global__ __launch_bounds__(256)
void coarse_scatter(const void* __restrict__ srcv, const void* __restrict__ dstv,
                    const unsigned* __restrict__ flags,
                    unsigned* __restrict__ c_cur, unsigned* __restrict__ packed) {
    __shared__ unsigned h[NB];
    const int t = threadIdx.x;
    for (int i = t; i < NB; i += 256) h[i] = 0;
    __syncthreads();
    const unsigned idx64 = flags[1];
    const int base = blockIdx.x * CHUNK_E;
    unsigned pk[CHUNK_E / 256];
#pragma unroll
    for (int j = 0; j < CHUNK_E / 256; ++j) {
        int e = base + j * 256 + t;
        unsigned p = 0xFFFFFFFFu;                      // sentinel
        if (e < N_EDGES) {
            int s, d;
            if (idx64) {
                s = (int)((const long long*)srcv)[e];
                d = (int)((const long long*)dstv)[e];
            } else {
                s = ((const int*)srcv)[e];
                d = ((const int*)dstv)[e];
            }
            s = min(max(s, 0), N_NODES - 1);
            d = min(max(d, 0), N_NODES - 1);
            p = ((unsigned)d << 16) | (unsigned)s;
            atomicAdd(&h[d >> 7], 1u);
        }
        pk[j] = p;
    }
    __syncthreads();
    // one reservation atomic per (block,bucket); h becomes the LDS write cursor
    for (int i = t; i < NB; i += 256) h[i] = atomicAdd(&c_cur[i], h[i]);
    __syncthreads();
#pragma unroll
    for (int j = 0; j < CHUNK_E / 256; ++j) {
        unsigned p = pk[j];
        if (p != 0xFFFFFFFFu) {
            unsigned pos = atomicAdd(&h[p >> 23], 1u); // p>>23 == dst>>7
            packed[pos] = p;
        }
    }
}

// ---------- kernel 5: per-bucket LDS-atomic min + fused epilogue ----------
// One block per bucket of 128 nodes. mn[128][64] ord-u32 minima in LDS (32 KB).
// Stream unsorted bucket edges: gather T16[src] row-quads, LDS atomicMin.
// Then out[node] = C[node] - min (in place on d_out).
__global__ __launch_bounds__(512)
void bucket_min(const unsigned* __restrict__ c_off, const unsigned* __restrict__ packed,
                const unsigned short* __restrict__ T16, const unsigned* __restrict__ flags,
                void* __restrict__ outv) {
    __shared__ unsigned mn[128 * 64];                  // 32 KB
    const unsigned fp32mode = flags[0];
    const int t = threadIdx.x;
    const int b = blockIdx.x;
#pragma unroll
    for (int i = 0; i < 16; ++i) mn[i * 512 + t] = 0xFFFFFFFFu;
    __syncthreads();
    const int estart = (int)c_off[b], eend = (int)c_off[b + 1];
    const int lane = t & 63, wv = t >> 6;              // 8 waves
    const int g = lane >> 4, fb = (lane & 15) << 2;    // 4 edges x 16 feature-quads
    int i = estart + wv * 4 + g;
    for (; i + 32 < eend; i += 64) {                   // 2 gathers in flight
        unsigned p0 = packed[i], p1 = packed[i + 32];
        uint2 v0 = *(const uint2*)(T16 + (int)(p0 & 0xFFFFu) * D + fb);
        uint2 v1 = *(const uint2*)(T16 + (int)(p1 & 0xFFFFu) * D + fb);
        unsigned* m0p = &mn[(int)((p0 >> 16) & 127u) * 64 + fb];
        unsigned* m1p = &mn[(int)((p1 >> 16) & 127u) * 64 + fb];
        atomicMin(m0p + 0, f2ord(b2f((unsigned short)v0.x)));
        atomicMin(m0p + 1, f2ord(b2f((unsigned short)(v0.x >> 16))));
        atomicMin(m0p + 2, f2ord(b2f((unsigned short)v0.y)));
        atomicMin(m0p + 3, f2ord(b2f((unsigned short)(v0.y >> 16))));
        atomicMin(m1p + 0, f2ord(b2f((unsigned short)v1.x)));
        atomicMin(m1p + 1, f2ord(b2f((unsigned short)(v1.x >> 16))));
        atomicMin(m1p + 2, f2ord(b2f((unsigned short)v1.y)));
        atomicMin(m1p + 3, f2ord(b2f((unsigned short)(v1.y >> 16))));
    }
    for (; i < eend; i += 32) {
        unsigned p0 = packed[i];
        uint2 v0 = *(const uint2*)(T16 + (int)(p0 & 0xFFFFu) * D + fb);
        unsigned* m0p = &mn[(int)((p0 >> 16) & 127u) * 64 + fb];
        atomicMin(m0p + 0, f2ord(b2f((unsigned short)v0.x)));
        atomicMin(m0p + 1, f2ord(b2f((unsigned short)(v0.x >> 16))));
        atomicMin(m0p + 2, f2ord(b2f((unsigned short)v0.y)));
        atomicMin(m0p + 3, f2ord(b2f((unsigned short)(v0.y >> 16))));
    }
    __syncthreads();
    // epilogue: 128 nodes x 16 float4-quads = 2048 slots
    const int node0 = b << 7;
    for (int sl = t; sl < 128 * 16; sl += 512) {
        const int row = sl >> 4;
        const int node = node0 + row;
        if (node >= N_NODES) break;                    // sl monotone per thread
        const int f4 = (sl & 15) << 2;
        const unsigned* mp = &mn[row * 64 + f4];
        float m0 = ord2f(mp[0]), m1 = ord2f(mp[1]);
        float m2 = ord2f(mp[2]), m3 = ord2f(mp[3]);
        if (fp32mode) {
            float4* C = (float4*)((float*)outv + node * D + f4);
            float4 c = *C;
            *C = make_float4(c.x - m0, c.y - m1, c.z - m2, c.w - m3);
        } else {
            unsigned short* C = (unsigned short*)outv + node * D + f4;
            uint2 c = *(uint2*)C;
            unsigned lo = (unsigned)f2b(b2f((unsigned short)c.x) - m0)
                        | ((unsigned)f2b(b2f((unsigned short)(c.x >> 16)) - m1) << 16);
            unsigned hi = (unsigned)f2b(b2f((unsigned short)c.y) - m2)
                        | ((unsigned)f2b(b2f((unsigned short)(c.y >> 16)) - m3) << 16);
            *(uint2*)C = make_uint2(lo, hi);
        }
    }
}

extern "C" void kernel_launch(void* const* d_in, const int* in_sizes, int n_in,
                              void* d_out, int out_size, void* d_ws, size_t ws_size,
                              hipStream_t stream) {
    // ws layout (~9.6 MB used):
    char* p = (char*)d_ws;
    unsigned*       flags    = (unsigned*)p;                     // 256 B
    unsigned*       c_cnt    = (unsigned*)(p + 256);             // 392*4 -> 2048
    unsigned*       c_off    = (unsigned*)(p + 2304);            // 2048
    unsigned*       c_cur    = (unsigned*)(p + 4352);            // 2048
    unsigned*       packed   = (unsigned*)(p + 6400);            // 3.2 MB
    unsigned short* T16      = (unsigned short*)(p + 6400 + 3200000);   // 6.4 MB
    unsigned short* WTfrag   = (unsigned short*)(p + 6400 + 3200000 + 6400000);        // 8 KB
    unsigned short* WPfrag   = (unsigned short*)(p + 6400 + 3200000 + 6400000 + 8192); // 8 KB
    float*          bias_sum = (float*)(p + 6400 + 3200000 + 6400000 + 16384);         // 256 B

    setup<<<1, 256, 0, stream>>>(d_in[0], d_in[1], d_in[3], d_in[4], d_in[5], d_in[6],
                                 flags, c_cnt, WTfrag, WPfrag, bias_sum);
    gemm_count<<<GEMM_BLKS + NPB, 256, 0, stream>>>(d_in[0], WTfrag, WPfrag, bias_sum,
                                                    d_in[2], flags, c_cnt, T16, d_out);
    scanNB<<<1, 512, 0, stream>>>(c_cnt, c_off, c_cur);
    coarse_scatter<<<NPB, 256, 0, stream>>>(d_in[1], d_in[2], flags, c_cur, packed);
    bucket_min<<<NB, 512, 0, stream>>>(c_off, packed, T16, flags, d_out);
}

// Round 13
// 143.762 us; speedup vs baseline: 1.4569x; 1.0695x over previous
//
#include <hip/hip_runtime.h>
#include <hip/hip_bf16.h>

#define N_NODES 50000
#define N_EDGES 800000
#define D 64
#define NB 391        // coarse buckets: dst>>7 -> 0..390 (128 nodes/bucket)
#define CHUNK_E 2048  // edges per partition block
#define NPB 391       // ceil(800000/2048)
#define NSTRIP 3125   // N_NODES/16
#define GEMM_BLKS 782 // ceil(3125/4)

typedef __attribute__((ext_vector_type(8))) short short8v;   // 8 bf16 (4 VGPRs)
typedef __attribute__((ext_vector_type(4))) float float4v;   // 4 fp32 acc

// ---------- helpers ----------
__device__ __forceinline__ float b2f(unsigned short h) {
    return __uint_as_float(((unsigned)h) << 16);
}
__device__ __forceinline__ unsigned short f2b(float f) {
    __hip_bfloat16 t = __float2bfloat16(f);
    return *reinterpret_cast<unsigned short*>(&t);
}
__device__ __forceinline__ short f2bs(float f) { return (short)f2b(f); }
// monotonic float<->uint encoding: unsigned min == float min
__device__ __forceinline__ unsigned f2ord(float f) {
    unsigned u = __float_as_uint(f);
    return (u & 0x80000000u) ? ~u : (u | 0x80000000u);
}
__device__ __forceinline__ float ord2f(unsigned o) {
    return __uint_as_float((o & 0x80000000u) ? (o ^ 0x80000000u) : ~o);
}

// ---------- kernel 1: setup = detect + prep_w + zero c_cnt (1 block) ----------
__global__ __launch_bounds__(256)
void setup(const void* __restrict__ featv, const void* __restrict__ srcv,
           const void* __restrict__ Wtv, const void* __restrict__ btv,
           const void* __restrict__ Wpv, const void* __restrict__ bpv,
           unsigned* __restrict__ flags, unsigned* __restrict__ c_cnt,
           unsigned short* __restrict__ WTfrag, unsigned short* __restrict__ WPfrag,
           float* __restrict__ bias_sum) {
    __shared__ unsigned sf[2];
    const int t = threadIdx.x;
    if (t < 64) {
        const unsigned short* p = (const unsigned short*)featv;
        float x = b2f(p[2 * t]);
        float a = fabsf(x);
        bool insane = !(a <= 64.f) || (x != 0.f && a < 9.3132e-10f);
        unsigned long long m = __ballot(insane);
        if (t == 0) sf[0] = (__popcll(m) >= 8) ? 1u : 0u;
    } else if (t < 128) {
        const int* s32 = (const int*)srcv;
        int v = s32[2 * (t - 64) + 1];
        unsigned long long m = __ballot(v == 0);
        if (t == 64) sf[1] = (__popcll(m) >= 32) ? 1u : 0u;
    }
    __syncthreads();
    const unsigned fp32mode = sf[0];
    if (t < 2) flags[t] = sf[t];
    for (int i = t; i < NB; i += 256) c_cnt[i] = 0;
#pragma unroll
    for (int i = 0; i < 16; ++i) {
        int e = i * 256 + t;                           // coalesced read
        int k = e >> 6, n = e & 63;
        float vt, vp;
        if (fp32mode) {
            vt = ((const float*)Wtv)[e];
            vp = ((const float*)Wpv)[e];
        } else {
            vt = b2f(((const unsigned short*)Wtv)[e]);
            vp = b2f(((const unsigned short*)Wpv)[e]);
        }
        WTfrag[n * 64 + k] = f2b(vt);
        WPfrag[n * 64 + k] = f2b(vp);
    }
    if (t < 64) {
        if (fp32mode)
            bias_sum[t] = ((const float*)btv)[t] + ((const float*)bpv)[t];
        else
            bias_sum[t] = b2f(((const unsigned short*)btv)[t])
                        + b2f(((const unsigned short*)bpv)[t]);
    }
}

// ---------- kernel 2: coarse dst histogram (dst>>7) ----------
__global__ __launch_bounds__(256)
void hist(const void* __restrict__ dstv, const unsigned* __restrict__ flags,
          unsigned* __restrict__ c_cnt) {
    __shared__ unsigned cnt[NB];
    const int t = threadIdx.x;
    for (int i = t; i < NB; i += 256) cnt[i] = 0;
    __syncthreads();
    const unsigned idx64 = flags[1];
    const int base = blockIdx.x * CHUNK_E;
#pragma unroll
    for (int j = 0; j < CHUNK_E / 256; ++j) {
        int e = base + j * 256 + t;
        if (e < N_EDGES) {
            int d = idx64 ? (int)((const long long*)dstv)[e] : ((const int*)dstv)[e];
            d = min(max(d, 0), N_NODES - 1);
            atomicAdd(&cnt[d >> 7], 1u);
        }
    }
    __syncthreads();
    for (int i = t; i < NB; i += 256)
        if (cnt[i]) atomicAdd(&c_cnt[i], cnt[i]);
}

// ---------- kernel 3: scan of NB coarse counts -> c_off, c_cur ----------
__global__ __launch_bounds__(512)
void scanNB(const unsigned* __restrict__ c_cnt, unsigned* __restrict__ c_off,
            unsigned* __restrict__ c_cur) {
    __shared__ unsigned sm[512];
    const int t = threadIdx.x;
    unsigned v = (t < NB) ? c_cnt[t] : 0u;
    sm[t] = v;
    __syncthreads();
    for (int off = 1; off < 512; off <<= 1) {
        unsigned u = (t >= off) ? sm[t - off] : 0u;
        __syncthreads();
        sm[t] += u;
        __syncthreads();
    }
    if (t < NB) { c_off[t] = sm[t] - v; c_cur[t] = sm[t] - v; }
    if (t == 0) c_off[NB] = N_EDGES;
}

// ---------- kernel 4: fused [MFMA node transforms ∥ coarse partition] ----------
// blocks [0, GEMM_BLKS): T=feat@Wt -> T16 ; C=feat@(Wt+Wp)+b -> d_out
// blocks [GEMM_BLKS, +NPB): partition packed (dst<<16|src) into buckets
// (independent phases on disjoint resources — overlap instead of serialize)
__global__ __launch_bounds__(256)
void gemm_scatter(const void* __restrict__ featv,
                  const unsigned short* __restrict__ WTfrag,
                  const unsigned short* __restrict__ WPfrag,
                  const float* __restrict__ bias_sum,
                  const void* __restrict__ srcv, const void* __restrict__ dstv,
                  const unsigned* __restrict__ flags,
                  unsigned* __restrict__ c_cur, unsigned* __restrict__ packed,
                  unsigned short* __restrict__ T16, void* __restrict__ outv) {
    const unsigned fp32mode = flags[0];
    if (blockIdx.x < GEMM_BLKS) {
        const int lane = threadIdx.x & 63;
        const int wid  = threadIdx.x >> 6;
        const int w = blockIdx.x * 4 + wid;            // one 16-row strip per wave
        if (w >= NSTRIP) return;
        const int m = lane & 15, q = lane >> 4;

        short8v A0, A1;
        if (fp32mode) {
            const float* fr = (const float*)featv + (w * 16 + m) * D + q * 8;
            float4 l0 = *(const float4*)(fr);
            float4 h0 = *(const float4*)(fr + 4);
            float4 l1 = *(const float4*)(fr + 32);
            float4 h1 = *(const float4*)(fr + 36);
            A0 = (short8v){f2bs(l0.x), f2bs(l0.y), f2bs(l0.z), f2bs(l0.w),
                           f2bs(h0.x), f2bs(h0.y), f2bs(h0.z), f2bs(h0.w)};
            A1 = (short8v){f2bs(l1.x), f2bs(l1.y), f2bs(l1.z), f2bs(l1.w),
                           f2bs(h1.x), f2bs(h1.y), f2bs(h1.z), f2bs(h1.w)};
        } else {
            const short* fr = (const short*)featv + (w * 16 + m) * D + q * 8;
            A0 = *(const short8v*)fr;
            A1 = *(const short8v*)(fr + 32);
        }

        const short8v* BT = (const short8v*)WTfrag;    // idx = col*8 + h*4 + q
        const short8v* BP = (const short8v*)WPfrag;
        float* Cf  = (float*)outv;
        unsigned short* Ch = (unsigned short*)outv;

#pragma unroll
        for (int c = 0; c < 4; ++c) {
            const int col = 16 * c + m;
            short8v Bt0 = BT[col * 8 + q];
            short8v Bt1 = BT[col * 8 + 4 + q];
            short8v Bp0 = BP[col * 8 + q];
            short8v Bp1 = BP[col * 8 + 4 + q];
            float bs = bias_sum[col];
            float4v accT = (float4v){0.f, 0.f, 0.f, 0.f};
            float4v accP = (float4v){bs, bs, bs, bs};
            accT = __builtin_amdgcn_mfma_f32_16x16x32_bf16(A0, Bt0, accT, 0, 0, 0);
            accT = __builtin_amdgcn_mfma_f32_16x16x32_bf16(A1, Bt1, accT, 0, 0, 0);
            accP = __builtin_amdgcn_mfma_f32_16x16x32_bf16(A0, Bp0, accP, 0, 0, 0);
            accP = __builtin_amdgcn_mfma_f32_16x16x32_bf16(A1, Bp1, accP, 0, 0, 0);
            // C/D layout: col = lane&15 (+16c), row = q*4 + reg
#pragma unroll
            for (int r = 0; r < 4; ++r) {
                const int row = w * 16 + q * 4 + r;
                T16[row * D + col] = f2b(accT[r]);
                if (fp32mode) Cf[row * D + col] = accT[r] + accP[r];
                else          Ch[row * D + col] = f2b(accT[r] + accP[r]);
            }
        }
    } else {
        // ---- coarse partition branch ----
        __shared__ unsigned h[NB];
        const int t = threadIdx.x;
        for (int i = t; i < NB; i += 256) h[i] = 0;
        __syncthreads();
        const unsigned idx64 = flags[1];
        const int base = (blockIdx.x - GEMM_BLKS) * CHUNK_E;
        unsigned pk[CHUNK_E / 256];
#pragma unroll
        for (int j = 0; j < CHUNK_E / 256; ++j) {
            int e = base + j * 256 + t;
            unsigned p = 0xFFFFFFFFu;                  // sentinel
            if (e < N_EDGES) {
                int s, d;
                if (idx64) {
                    s = (int)((const long long*)srcv)[e];
                    d = (int)((const long long*)dstv)[e];
                } else {
                    s = ((const int*)srcv)[e];
                    d = ((const int*)dstv)[e];
                }
                s = min(max(s, 0), N_NODES - 1);
                d = min(max(d, 0), N_NODES - 1);
                p = ((unsigned)d << 16) | (unsigned)s;
                atomicAdd(&h[d >> 7], 1u);
            }
            pk[j] = p;
        }
        __syncthreads();
        // one reservation atomic per (block,bucket); h becomes the LDS cursor
        for (int i = t; i < NB; i += 256) h[i] = atomicAdd(&c_cur[i], h[i]);
        __syncthreads();
#pragma unroll
        for (int j = 0; j < CHUNK_E / 256; ++j) {
            unsigned p = pk[j];
            if (p != 0xFFFFFFFFu) {
                unsigned pos = atomicAdd(&h[p >> 23], 1u); // p>>23 == dst>>7
                packed[pos] = p;
            }
        }
    }
}

// ---------- kernel 5: per-bucket LDS-atomic min + fused epilogue ----------
// One block per bucket of 128 nodes. mn[128][64] ord-u32 minima in LDS (32 KB).
__global__ __launch_bounds__(512)
void bucket_min(const unsigned* __restrict__ c_off, const unsigned* __restrict__ packed,
                const unsigned short* __restrict__ T16, const unsigned* __restrict__ flags,
                void* __restrict__ outv) {
    __shared__ unsigned mn[128 * 64];                  // 32 KB
    const unsigned fp32mode = flags[0];
    const int t = threadIdx.x;
    const int b = blockIdx.x;
#pragma unroll
    for (int i = 0; i < 16; ++i) mn[i * 512 + t] = 0xFFFFFFFFu;
    __syncthreads();
    const int estart = (int)c_off[b], eend = (int)c_off[b + 1];
    const int lane = t & 63, wv = t >> 6;              // 8 waves
    const int g = lane >> 4, fb = (lane & 15) << 2;    // 4 edges x 16 feature-quads
    int i = estart + wv * 4 + g;
    for (; i + 96 < eend; i += 128) {                  // 4 gathers in flight
        unsigned p0 = packed[i],      p1 = packed[i + 32];
        unsigned p2 = packed[i + 64], p3 = packed[i + 96];
        uint2 v0 = *(const uint2*)(T16 + (int)(p0 & 0xFFFFu) * D + fb);
        uint2 v1 = *(const uint2*)(T16 + (int)(p1 & 0xFFFFu) * D + fb);
        uint2 v2 = *(const uint2*)(T16 + (int)(p2 & 0xFFFFu) * D + fb);
        uint2 v3 = *(const uint2*)(T16 + (int)(p3 & 0xFFFFu) * D + fb);
        unsigned* m0p = &mn[(int)((p0 >> 16) & 127u) * 64 + fb];
        unsigned* m1p = &mn[(int)((p1 >> 16) & 127u) * 64 + fb];
        unsigned* m2p = &mn[(int)((p2 >> 16) & 127u) * 64 + fb];
        unsigned* m3p = &mn[(int)((p3 >> 16) & 127u) * 64 + fb];
        atomicMin(m0p + 0, f2ord(b2f((unsigned short)v0.x)));
        atomicMin(m0p + 1, f2ord(b2f((unsigned short)(v0.x >> 16))));
        atomicMin(m0p + 2, f2ord(b2f((unsigned short)v0.y)));
        atomicMin(m0p + 3, f2ord(b2f((unsigned short)(v0.y >> 16))));
        atomicMin(m1p + 0, f2ord(b2f((unsigned short)v1.x)));
        atomicMin(m1p + 1, f2ord(b2f((unsigned short)(v1.x >> 16))));
        atomicMin(m1p + 2, f2ord(b2f((unsigned short)v1.y)));
        atomicMin(m1p + 3, f2ord(b2f((unsigned short)(v1.y >> 16))));
        atomicMin(m2p + 0, f2ord(b2f((unsigned short)v2.x)));
        atomicMin(m2p + 1, f2ord(b2f((unsigned short)(v2.x >> 16))));
        atomicMin(m2p + 2, f2ord(b2f((unsigned short)v2.y)));
        atomicMin(m2p + 3, f2ord(b2f((unsigned short)(v2.y >> 16))));
        atomicMin(m3p + 0, f2ord(b2f((unsigned short)v3.x)));
        atomicMin(m3p + 1, f2ord(b2f((unsigned short)(v3.x >> 16))));
        atomicMin(m3p + 2, f2ord(b2f((unsigned short)v3.y)));
        atomicMin(m3p + 3, f2ord(b2f((unsigned short)(v3.y >> 16))));
    }
    for (; i < eend; i += 32) {
        unsigned p0 = packed[i];
        uint2 v0 = *(const uint2*)(T16 + (int)(p0 & 0xFFFFu) * D + fb);
        unsigned* m0p = &mn[(int)((p0 >> 16) & 127u) * 64 + fb];
        atomicMin(m0p + 0, f2ord(b2f((unsigned short)v0.x)));
        atomicMin(m0p + 1, f2ord(b2f((unsigned short)(v0.x >> 16))));
        atomicMin(m0p + 2, f2ord(b2f((unsigned short)v0.y)));
        atomicMin(m0p + 3, f2ord(b2f((unsigned short)(v0.y >> 16))));
    }
    __syncthreads();
    // epilogue: 128 nodes x 16 float4-quads = 2048 slots
    const int node0 = b << 7;
    for (int sl = t; sl < 128 * 16; sl += 512) {
        const int row = sl >> 4;
        const int node = node0 + row;
        if (node >= N_NODES) break;                    // sl monotone per thread
        const int f4 = (sl & 15) << 2;
        const unsigned* mp = &mn[row * 64 + f4];
        float m0 = ord2f(mp[0]), m1 = ord2f(mp[1]);
        float m2 = ord2f(mp[2]), m3 = ord2f(mp[3]);
        if (fp32mode) {
            float4* C = (float4*)((float*)outv + node * D + f4);
            float4 c = *C;
            *C = make_float4(c.x - m0, c.y - m1, c.z - m2, c.w - m3);
        } else {
            unsigned short* C = (unsigned short*)outv + node * D + f4;
            uint2 c = *(uint2*)C;
            unsigned lo = (unsigned)f2b(b2f((unsigned short)c.x) - m0)
                        | ((unsigned)f2b(b2f((unsigned short)(c.x >> 16)) - m1) << 16);
            unsigned hi = (unsigned)f2b(b2f((unsigned short)c.y) - m2)
                        | ((unsigned)f2b(b2f((unsigned short)(c.y >> 16)) - m3) << 16);
            *(uint2*)C = make_uint2(lo, hi);
        }
    }
}

extern "C" void kernel_launch(void* const* d_in, const int* in_sizes, int n_in,
                              void* d_out, int out_size, void* d_ws, size_t ws_size,
                              hipStream_t stream) {
    // ws layout (~9.6 MB used):
    char* p = (char*)d_ws;
    unsigned*       flags    = (unsigned*)p;                     // 256 B
    unsigned*       c_cnt    = (unsigned*)(p + 256);             // 392*4 -> 2048
    unsigned*       c_off    = (unsigned*)(p + 2304);            // 2048
    unsigned*       c_cur    = (unsigned*)(p + 4352);            // 2048
    unsigned*       packed   = (unsigned*)(p + 6400);            // 3.2 MB
    unsigned short* T16      = (unsigned short*)(p + 6400 + 3200000);   // 6.4 MB
    unsigned short* WTfrag   = (unsigned short*)(p + 6400 + 3200000 + 6400000);        // 8 KB
    unsigned short* WPfrag   = (unsigned short*)(p + 6400 + 3200000 + 6400000 + 8192); // 8 KB
    float*          bias_sum = (float*)(p + 6400 + 3200000 + 6400000 + 16384);         // 256 B

    setup<<<1, 256, 0, stream>>>(d_in[0], d_in[1], d_in[3], d_in[4], d_in[5], d_in[6],
                                 flags, c_cnt, WTfrag, WPfrag, bias_sum);
    hist<<<NPB, 256, 0, stream>>>(d_in[2], flags, c_cnt);
    scanNB<<<1, 512, 0, stream>>>(c_cnt, c_off, c_cur);
    gemm_scatter<<<GEMM_BLKS + NPB, 256, 0, stream>>>(d_in[0], WTfrag, WPfrag, bias_sum,
                                                      d_in[1], d_in[2], flags,
                                                      c_cur, packed, T16, d_out);
    bucket_min<<<NB, 512, 0, stream>>>(c_off, packed, T16, flags, d_out);
}